// Round 7
// baseline (1214.834 us; speedup 1.0000x reference)
//
#include <hip/hip_runtime.h>
#include <math.h>

// FactorizationMachine: out = sigmoid( X@fc_w + fc_b + 0.5*( sum_d (X@w)_d^2 - (X^2)@g ) )
//
// R6 redesign. Cumulative diagnosis R0-R5: every variant was concurrency-starved
// (1 wave/SIMD register cliff, or barrier-locked shallow DMA pipeline). Fix all:
//  - Phase 0: precompute wT[d][f] (transpose) and gneg[f] = -0.5*sum_d w^2 in ws.
//    Phase-1 W loads become lane-coalesced; g-trick costs 0 regs.
//  - Phase 1: wave = d-quarter (32 acc + 2 scalar), ~100 VGPR, launch_bounds(256,4)
//    -> 4 waves/SIMD, NO LDS, NO barriers. 14 independent coalesced loads/iter/wave.
//    X cached (shared by 4 waves via L1/L2); 1024 blocks = 512 row-groups x KSPLIT 2,
//    chunk = blockIdx&1 -> chunk parity pinned to XCD parity (W_T hot set 1.7 MB/L2).
//  - Phase 2: combine 2 chunk-partials/row + sigmoid.

constexpr int B_ROWS  = 4096;
constexpr int F_FEAT  = 50000;
constexpr int NF4     = F_FEAT / 4;          // 12500
constexpr int D_FAC   = 16;
constexpr int ROWS    = 8;
constexpr int THREADS = 256;
constexpr int KSPLIT  = 2;
constexpr int CHUNK_F4 = NF4 / KSPLIT;       // 6250
constexpr int NGROUP  = B_ROWS / ROWS;       // 512
constexpr int NBLK1   = NGROUP * KSPLIT;     // 1024
constexpr int PVALS   = 34;                  // 32 s + 2 scalars per wave

// float offsets into ws (all multiples of 4 -> 16B aligned)
constexpr size_t WT_OFF = 0;                         // 16 * 50000 floats
constexpr size_t G_OFF  = (size_t)D_FAC * F_FEAT;    // 800000
constexpr size_t P_OFF  = G_OFF + 50000;             // 850000

typedef float f32x4 __attribute__((ext_vector_type(4)));

// ---------------- Phase 0: W transpose + gneg ----------------
__global__ __launch_bounds__(256)
void fm_prep(const float* __restrict__ W, float* __restrict__ ws)
{
    const int f = blockIdx.x * 256 + threadIdx.x;
    if (f >= F_FEAT) return;
    const f32x4* W4 = reinterpret_cast<const f32x4*>(W);
    f32x4 wv[4];
#pragma unroll
    for (int q = 0; q < 4; ++q) wv[q] = W4[(size_t)f * 4 + q];
    float gs = 0.f;
#pragma unroll
    for (int t = 0; t < D_FAC; ++t) {
        const float wd = wv[t >> 2][t & 3];
        gs = fmaf(wd, wd, gs);
        ws[WT_OFF + (size_t)t * F_FEAT + f] = wd;    // coalesced per t
    }
    ws[G_OFF + f] = -0.5f * gs;
}

// ---------------- Phase 1: main sweep ----------------
__global__ __launch_bounds__(THREADS, 4)   // 4 blocks/CU -> 16 waves/CU, VGPR<=128
void fm_main(const float* __restrict__ X,
             const float* __restrict__ fcw,
             const float* __restrict__ wt,      // ws + WT_OFF
             const float* __restrict__ gneg,    // ws + G_OFF
             float* __restrict__ pout)          // ws + P_OFF
{
    const int tid  = threadIdx.x;
    const int lane = tid & 63;
    const int dg   = tid >> 6;                 // wave id = d-quarter
    const int c    = blockIdx.x & (KSPLIT - 1);
    const int grp  = blockIdx.x >> 1;
    const int row0 = grp * ROWS;
    const int beg  = c * CHUNK_F4;
    const int end  = beg + CHUNK_F4;

    const f32x4* X4  = reinterpret_cast<const f32x4*>(X);
    const f32x4* FW4 = reinterpret_cast<const f32x4*>(fcw);
    const f32x4* WT4 = reinterpret_cast<const f32x4*>(wt);
    const f32x4* G4  = reinterpret_cast<const f32x4*>(gneg);

    float s[ROWS][4];                          // S[row][4dg+k] partials
    float sc0 = 0.f, sc1 = 0.f;                // linear - 0.5*sum_sq for rows 2dg,2dg+1
#pragma unroll
    for (int r = 0; r < ROWS; ++r)
#pragma unroll
        for (int k = 0; k < 4; ++k) s[r][k] = 0.f;

    const int r2 = 2 * dg;

    for (int f4 = beg + lane; f4 < end; f4 += 64) {
        f32x4 xv[ROWS];                        // 8 coalesced X streams (L1-shared x4 waves)
#pragma unroll
        for (int r = 0; r < ROWS; ++r)
            xv[r] = X4[(size_t)(row0 + r) * NF4 + f4];

        f32x4 wt4[4];                          // this wave's 4 d-columns, coalesced
#pragma unroll
        for (int k = 0; k < 4; ++k)
            wt4[k] = WT4[(size_t)(4 * dg + k) * NF4 + f4];

        const f32x4 fw = FW4[f4];
        const f32x4 gn = G4[f4];

#pragma unroll
        for (int j = 0; j < 4; ++j) {
#pragma unroll
            for (int r = 0; r < ROWS; ++r) {
                const float x = xv[r][j];
                s[r][0] = fmaf(x, wt4[0][j], s[r][0]);
                s[r][1] = fmaf(x, wt4[1][j], s[r][1]);
                s[r][2] = fmaf(x, wt4[2][j], s[r][2]);
                s[r][3] = fmaf(x, wt4[3][j], s[r][3]);
            }
            const float xa = xv[r2][j];
            const float xb = xv[r2 + 1][j];
            sc0 = fmaf(xa, fw[j], sc0);
            sc0 = fmaf(xa * xa, gn[j], sc0);
            sc1 = fmaf(xb, fw[j], sc1);
            sc1 = fmaf(xb * xb, gn[j], sc1);
        }
    }

    // per-wave butterfly reduce; value i lands on lane i; coalesced store
    float keep = 0.f;
    int idx = 0;
#pragma unroll
    for (int r = 0; r < ROWS; ++r)
#pragma unroll
        for (int k = 0; k < 4; ++k) {
            float v = s[r][k];
#pragma unroll
            for (int m = 32; m >= 1; m >>= 1) v += __shfl_xor(v, m, 64);
            if (lane == idx) keep = v;
            ++idx;
        }
    {
        float v = sc0;
#pragma unroll
        for (int m = 32; m >= 1; m >>= 1) v += __shfl_xor(v, m, 64);
        if (lane == 32) keep = v;
        v = sc1;
#pragma unroll
        for (int m = 32; m >= 1; m >>= 1) v += __shfl_xor(v, m, 64);
        if (lane == 33) keep = v;
    }
    float* base = pout + ((size_t)blockIdx.x * 4 + dg) * PVALS;
    if (lane < PVALS) base[lane] = keep;
}

// ---------------- Phase 2: combine + sigmoid ----------------
__global__ __launch_bounds__(256)
void fm_final(const float* __restrict__ pout,
              const float* __restrict__ fcb,
              float* __restrict__ out)
{
    const int r = blockIdx.x * 256 + threadIdx.x;
    if (r >= B_ROWS) return;
    const int grp = r >> 3;
    const int rr  = r & 7;

    float sD[D_FAC];
#pragma unroll
    for (int d = 0; d < D_FAC; ++d) sD[d] = 0.f;
    float sc = 0.f;

#pragma unroll
    for (int c = 0; c < KSPLIT; ++c) {
        const size_t blk = (size_t)grp * KSPLIT + c;
#pragma unroll
        for (int dg = 0; dg < 4; ++dg) {
            const float* p = pout + (blk * 4 + dg) * PVALS;
#pragma unroll
            for (int k = 0; k < 4; ++k) sD[4 * dg + k] += p[rr * 4 + k];
        }
        const float* ps = pout + (blk * 4 + (rr >> 1)) * PVALS;
        sc += ps[32 + (rr & 1)];
    }

    float ss = 0.f;
#pragma unroll
    for (int d = 0; d < D_FAC; ++d) ss = fmaf(sD[d], sD[d], ss);

    const float logit = sc + fcb[0] + 0.5f * ss;
    out[r] = 1.0f / (1.0f + expf(-logit));
}

extern "C" void kernel_launch(void* const* d_in, const int* in_sizes, int n_in,
                              void* d_out, int out_size, void* d_ws, size_t ws_size,
                              hipStream_t stream)
{
    const float* X   = (const float*)d_in[0];
    const float* fcw = (const float*)d_in[1];
    const float* fcb = (const float*)d_in[2];
    const float* W   = (const float*)d_in[3];
    float* out = (float*)d_out;
    float* ws  = (float*)d_ws;   // uses ~4 MB

    hipLaunchKernelGGL(fm_prep, dim3((F_FEAT + 255) / 256), dim3(256), 0, stream,
                       W, ws);
    hipLaunchKernelGGL(fm_main, dim3(NBLK1), dim3(THREADS), 0, stream,
                       X, fcw, ws + WT_OFF, ws + G_OFF, ws + P_OFF);
    hipLaunchKernelGGL(fm_final, dim3((B_ROWS + 255) / 256), dim3(256), 0, stream,
                       ws + P_OFF, fcb, out);
}

// Round 8
// 372.979 us; speedup vs baseline: 3.2571x; 3.2571x over previous
//
#include <hip/hip_runtime.h>
#include <math.h>

// FactorizationMachine: out = sigmoid( X@fc_w + fc_b + 0.5*( sum_d (X@w)_d^2 - (X^2)@g ) )
//
// R7 = R6 minus the scratch spill. R6's counters: VGPR_Count=44, WRITE_SIZE=3.1GB
// == 1024blk x 256thr x 98it x 8 float4 — the xv[] register array was demoted to
// scratch because xv[r2][j] used a RUNTIME index (r2 = 2*dg; rule #20). Fix: the
// scalar-term rows are re-loaded as named loads (runtime ADDRESS, L1-hot), all
// register-array indices compile-time. Structure unchanged:
//  - Phase 0: wT[d][f] transpose + gneg[f] = -0.5*sum_d w^2 into ws.
//  - Phase 1: wave = d-quarter (32 acc), no LDS, no barriers, launch_bounds(256,4)
//    -> 4 blocks/CU (45% occupancy measured in R6), 16 coalesced loads/iter/wave.
//  - Phase 2: combine KSPLIT=2 partials + sigmoid (validated, absmax 1.9e-9).

constexpr int B_ROWS  = 4096;
constexpr int F_FEAT  = 50000;
constexpr int NF4     = F_FEAT / 4;          // 12500
constexpr int D_FAC   = 16;
constexpr int ROWS    = 8;
constexpr int THREADS = 256;
constexpr int KSPLIT  = 2;
constexpr int CHUNK_F4 = NF4 / KSPLIT;       // 6250
constexpr int NGROUP  = B_ROWS / ROWS;       // 512
constexpr int NBLK1   = NGROUP * KSPLIT;     // 1024
constexpr int PVALS   = 34;                  // 32 s + 2 scalars per wave

constexpr size_t WT_OFF = 0;                         // 16 * 50000 floats
constexpr size_t G_OFF  = (size_t)D_FAC * F_FEAT;    // 800000
constexpr size_t P_OFF  = G_OFF + 50000;             // 850000

typedef float f32x4 __attribute__((ext_vector_type(4)));

// ---------------- Phase 0: W transpose + gneg ----------------
__global__ __launch_bounds__(256)
void fm_prep(const float* __restrict__ W, float* __restrict__ ws)
{
    const int f = blockIdx.x * 256 + threadIdx.x;
    if (f >= F_FEAT) return;
    const f32x4* W4 = reinterpret_cast<const f32x4*>(W);
    f32x4 wv[4];
#pragma unroll
    for (int q = 0; q < 4; ++q) wv[q] = W4[(size_t)f * 4 + q];
    float gs = 0.f;
#pragma unroll
    for (int t = 0; t < D_FAC; ++t) {
        const float wd = wv[t >> 2][t & 3];
        gs = fmaf(wd, wd, gs);
        ws[WT_OFF + (size_t)t * F_FEAT + f] = wd;    // coalesced per t
    }
    ws[G_OFF + f] = -0.5f * gs;
}

// ---------------- Phase 1: main sweep ----------------
__global__ __launch_bounds__(THREADS, 4)   // 4 waves/EU target, VGPR cap 128
void fm_main(const float* __restrict__ X,
             const float* __restrict__ fcw,
             const float* __restrict__ wt,      // ws + WT_OFF
             const float* __restrict__ gneg,    // ws + G_OFF
             float* __restrict__ pout)          // ws + P_OFF
{
    const int tid  = threadIdx.x;
    const int lane = tid & 63;
    const int dg   = tid >> 6;                 // wave id = d-quarter (wave-uniform)
    const int c    = blockIdx.x & (KSPLIT - 1);
    const int grp  = blockIdx.x >> 1;
    const int row0 = grp * ROWS;
    const int beg  = c * CHUNK_F4;
    const int end  = beg + CHUNK_F4;

    const f32x4* X4  = reinterpret_cast<const f32x4*>(X);
    const f32x4* FW4 = reinterpret_cast<const f32x4*>(fcw);
    const f32x4* WT4 = reinterpret_cast<const f32x4*>(wt);
    const f32x4* G4  = reinterpret_cast<const f32x4*>(gneg);

    float s[ROWS][4];                          // S[row][4dg+k] partials
    float sc0 = 0.f, sc1 = 0.f;                // linear - 0.5*sum_sq, rows 2dg,2dg+1
#pragma unroll
    for (int r = 0; r < ROWS; ++r)
#pragma unroll
        for (int k = 0; k < 4; ++k) s[r][k] = 0.f;

    // Runtime ADDRESSES (ok) for this wave's two scalar-term rows.
    const f32x4* Xa = X4 + (size_t)(row0 + 2 * dg)     * NF4;
    const f32x4* Xb = X4 + (size_t)(row0 + 2 * dg + 1) * NF4;

    for (int f4 = beg + lane; f4 < end; f4 += 64) {
        f32x4 xv[ROWS];                        // 8 coalesced X streams (L1-shared x4)
#pragma unroll
        for (int r = 0; r < ROWS; ++r)
            xv[r] = X4[(size_t)(row0 + r) * NF4 + f4];

        f32x4 wt4[4];                          // this wave's 4 d-columns, coalesced
#pragma unroll
        for (int k = 0; k < 4; ++k)
            wt4[k] = WT4[(size_t)(4 * dg + k) * NF4 + f4];

        const f32x4 fw  = FW4[f4];
        const f32x4 gn  = G4[f4];
        const f32x4 xa4 = Xa[f4];              // named loads, L1-hot duplicates
        const f32x4 xb4 = Xb[f4];              // (NOT runtime-indexed xv[] -> no scratch)

#pragma unroll
        for (int j = 0; j < 4; ++j) {
#pragma unroll
            for (int r = 0; r < ROWS; ++r) {
                const float x = xv[r][j];
                s[r][0] = fmaf(x, wt4[0][j], s[r][0]);
                s[r][1] = fmaf(x, wt4[1][j], s[r][1]);
                s[r][2] = fmaf(x, wt4[2][j], s[r][2]);
                s[r][3] = fmaf(x, wt4[3][j], s[r][3]);
            }
            const float xa = xa4[j];
            const float xb = xb4[j];
            sc0 = fmaf(xa, fw[j], sc0);
            sc0 = fmaf(xa * xa, gn[j], sc0);
            sc1 = fmaf(xb, fw[j], sc1);
            sc1 = fmaf(xb * xb, gn[j], sc1);
        }
    }

    // per-wave butterfly reduce; value i lands on lane i; coalesced store
    float keep = 0.f;
    int idx = 0;
#pragma unroll
    for (int r = 0; r < ROWS; ++r)
#pragma unroll
        for (int k = 0; k < 4; ++k) {
            float v = s[r][k];
#pragma unroll
            for (int m = 32; m >= 1; m >>= 1) v += __shfl_xor(v, m, 64);
            if (lane == idx) keep = v;
            ++idx;
        }
    {
        float v = sc0;
#pragma unroll
        for (int m = 32; m >= 1; m >>= 1) v += __shfl_xor(v, m, 64);
        if (lane == 32) keep = v;
        v = sc1;
#pragma unroll
        for (int m = 32; m >= 1; m >>= 1) v += __shfl_xor(v, m, 64);
        if (lane == 33) keep = v;
    }
    float* base = pout + ((size_t)blockIdx.x * 4 + dg) * PVALS;
    if (lane < PVALS) base[lane] = keep;
}

// ---------------- Phase 2: combine + sigmoid ----------------
__global__ __launch_bounds__(256)
void fm_final(const float* __restrict__ pout,
              const float* __restrict__ fcb,
              float* __restrict__ out)
{
    const int r = blockIdx.x * 256 + threadIdx.x;
    if (r >= B_ROWS) return;
    const int grp = r >> 3;
    const int rr  = r & 7;

    float sD[D_FAC];
#pragma unroll
    for (int d = 0; d < D_FAC; ++d) sD[d] = 0.f;
    float sc = 0.f;

#pragma unroll
    for (int c = 0; c < KSPLIT; ++c) {
        const size_t blk = (size_t)grp * KSPLIT + c;
#pragma unroll
        for (int dg = 0; dg < 4; ++dg) {
            const float* p = pout + (blk * 4 + dg) * PVALS;
#pragma unroll
            for (int k = 0; k < 4; ++k) sD[4 * dg + k] += p[rr * 4 + k];
        }
        const float* ps = pout + (blk * 4 + (rr >> 1)) * PVALS;
        sc += ps[32 + (rr & 1)];
    }

    float ss = 0.f;
#pragma unroll
    for (int d = 0; d < D_FAC; ++d) ss = fmaf(sD[d], sD[d], ss);

    const float logit = sc + fcb[0] + 0.5f * ss;
    out[r] = 1.0f / (1.0f + expf(-logit));
}

extern "C" void kernel_launch(void* const* d_in, const int* in_sizes, int n_in,
                              void* d_out, int out_size, void* d_ws, size_t ws_size,
                              hipStream_t stream)
{
    const float* X   = (const float*)d_in[0];
    const float* fcw = (const float*)d_in[1];
    const float* fcb = (const float*)d_in[2];
    const float* W   = (const float*)d_in[3];
    float* out = (float*)d_out;
    float* ws  = (float*)d_ws;   // uses ~4 MB

    hipLaunchKernelGGL(fm_prep, dim3((F_FEAT + 255) / 256), dim3(256), 0, stream,
                       W, ws);
    hipLaunchKernelGGL(fm_main, dim3(NBLK1), dim3(THREADS), 0, stream,
                       X, fcw, ws + WT_OFF, ws + G_OFF, ws + P_OFF);
    hipLaunchKernelGGL(fm_final, dim3((B_ROWS + 255) / 256), dim3(256), 0, stream,
                       ws + P_OFF, fcb, out);
}